// Round 6
// baseline (1061.102 us; speedup 1.0000x reference)
//
#include <hip/hip_runtime.h>

typedef unsigned short u16;
typedef __bf16 bf16x8 __attribute__((ext_vector_type(8)));
typedef float f32x4 __attribute__((ext_vector_type(4)));

#define Bsz 64
#define Ssz 64
#define Tsz 32
#define Hsz 512
#define Vsz 32000
#define NBLK 96      // recurrence blocks (64 B + 32 G); flag owners
#define NLBLK 160    // logits-GEMM blocks riding in coop's shadow
#define NTOT 256     // 1 block per CU, whole chip

static __device__ inline u16 f2bf(float f) {
    union { float f; unsigned u; } v; v.f = f;
    unsigned u = v.u;
    unsigned r = (u + 0x7FFFu + ((u >> 16) & 1u)) >> 16;
    return (u16)r;
}
static __device__ inline float bf2f(u16 v) {
    union { unsigned u; float f; } x; x.u = ((unsigned)v) << 16; return x.f;
}
static __device__ inline float tanh_fast(float x) {
    float e = __expf(2.f * x);
    return 1.f - 2.f / (e + 1.f);
}
// agent-scope write-through stores (sc1) — reach the IC coherence point
static __device__ inline void st_f32(float* p, float v) {
    __hip_atomic_store(p, v, __ATOMIC_RELAXED, __HIP_MEMORY_SCOPE_AGENT);
}
static __device__ inline void st_u32(unsigned* p, unsigned v) {
    __hip_atomic_store(p, v, __ATOMIC_RELAXED, __HIP_MEMORY_SCOPE_AGENT);
}

// direct-to-LDS 16B async copy (wave-uniform LDS base + lane*16 scatter)
#define GLOAD_LDS16(g, l) \
    __builtin_amdgcn_global_load_lds((const __attribute__((address_space(1))) void*)(g), \
                                     (__attribute__((address_space(3))) void*)(l), 16, 0, 0)

// ---------------- fused f32 -> bf16 weight prep ----------------
__global__ void prep_kernel(const float* __restrict__ enc, const float* __restrict__ Ua,
                            const float* __restrict__ Wa, const float* __restrict__ wih,
                            const float* __restrict__ whh, const float* __restrict__ Wo,
                            const float* __restrict__ ehid,
                            u16* __restrict__ encbf, u16* __restrict__ Uabf,
                            u16* __restrict__ Wabf, u16* __restrict__ wihbf,
                            u16* __restrict__ whhbf, u16* __restrict__ Wobf,
                            u16* __restrict__ h0bf) {
    const int n0 = 2097152, n1 = 262144, n2 = 262144, n3 = 1572864, n4 = 786432, n5 = 16384000, n6 = 32768;
    const int total = n0 + n1 + n2 + n3 + n4 + n5 + n6;
    for (int i = blockIdx.x * blockDim.x + threadIdx.x; i < total; i += gridDim.x * blockDim.x) {
        int j = i;
        if (j < n0) { encbf[j] = f2bf(enc[j]); continue; } j -= n0;
        if (j < n1) { Uabf[j] = f2bf(Ua[j]); continue; } j -= n1;
        if (j < n2) { Wabf[j] = f2bf(Wa[j]); continue; } j -= n2;
        if (j < n3) { wihbf[j] = f2bf(wih[j]); continue; } j -= n3;
        if (j < n4) { whhbf[j] = f2bf(whh[j]); continue; } j -= n4;
        if (j < n5) { Wobf[j] = f2bf(Wo[j]); continue; } j -= n5;
        h0bf[j] = f2bf(ehid[j]);
    }
}

// ---------------- embedding gather into xbuf[t][b][0:512] (bf16) ----------------
__global__ void embed_kernel(const int* __restrict__ target, const float* __restrict__ emb,
                             u16* __restrict__ xbuf) {
    int n = Tsz * Bsz * Hsz;
    for (int i = blockIdx.x * blockDim.x + threadIdx.x; i < n; i += gridDim.x * blockDim.x) {
        int t = i / (Bsz * Hsz);
        int rem = i % (Bsz * Hsz);
        int b = rem / Hsz, k = rem % Hsz;
        int id = (t == 0) ? 0 : target[b * Tsz + (t - 1)];
        xbuf[((size_t)t * Bsz + b) * 1024 + k] = f2bf(emb[(size_t)id * Hsz + k]);
    }
}

// ---------------- bf16 MFMA GEMM (Ua_keys only):  C = A @ Bw^T + bias ----------------
__global__ __launch_bounds__(256) void gemm_bt(const u16* __restrict__ A, const u16* __restrict__ Bw,
                                               const float* __restrict__ bias, float* __restrict__ out,
                                               int M, int N, int K) {
    __shared__ __align__(16) u16 As[128 * 32];
    __shared__ __align__(16) u16 Bs[128 * 32];
    int m0 = blockIdx.x * 128, n0 = blockIdx.y * 128;
    int tid = threadIdx.x, lane = tid & 63, wid = tid >> 6;
    int wm = wid & 1, wn = wid >> 1;
    f32x4 acc[4][4] = {};
    for (int k0 = 0; k0 < K; k0 += 32) {
        int e0 = wid * 64 + lane;
        int e1 = e0 + 256;
        GLOAD_LDS16(&A[(size_t)(m0 + (e0 >> 2)) * K + k0 + (e0 & 3) * 8], (char*)As + wid * 1024);
        GLOAD_LDS16(&A[(size_t)(m0 + (e1 >> 2)) * K + k0 + (e1 & 3) * 8], (char*)As + 4096 + wid * 1024);
        GLOAD_LDS16(&Bw[(size_t)(n0 + (e0 >> 2)) * K + k0 + (e0 & 3) * 8], (char*)Bs + wid * 1024);
        GLOAD_LDS16(&Bw[(size_t)(n0 + (e1 >> 2)) * K + k0 + (e1 & 3) * 8], (char*)Bs + 4096 + wid * 1024);
        __syncthreads();
        bf16x8 av[4], bvv[4];
        for (int mi = 0; mi < 4; ++mi)
            av[mi] = *(const bf16x8*)&As[(wm * 64 + mi * 16 + (lane & 15)) * 32 + (lane >> 4) * 8];
        for (int ni = 0; ni < 4; ++ni)
            bvv[ni] = *(const bf16x8*)&Bs[(wn * 64 + ni * 16 + (lane & 15)) * 32 + (lane >> 4) * 8];
        for (int mi = 0; mi < 4; ++mi)
            for (int ni = 0; ni < 4; ++ni)
                acc[mi][ni] = __builtin_amdgcn_mfma_f32_16x16x32_bf16(av[mi], bvv[ni], acc[mi][ni], 0, 0, 0);
        __syncthreads();
    }
    for (int mi = 0; mi < 4; ++mi)
        for (int ni = 0; ni < 4; ++ni) {
            int n = n0 + wn * 64 + ni * 16 + (lane & 15);
            float bb = bias[n];
            for (int r = 0; r < 4; ++r) {
                int m = m0 + wm * 64 + mi * 16 + (lane >> 4) * 4 + r;
                out[(size_t)m * N + n] = acc[mi][ni][r] + bb;
            }
        }
}

// ---------------- flag-array sync (no RMW, no leader) ----------------
static __device__ inline void arrive(unsigned* bar, int slot, unsigned val, int tid) {
    asm volatile("s_waitcnt vmcnt(0)" ::: "memory");
    __syncthreads();
    if (tid == 0) st_u32(&bar[slot * 32], val);
}
static __device__ inline void pollflags(unsigned* bar, int base, int n, unsigned target, int tid) {
    if (tid < n) {
        unsigned* p = &bar[(base + tid) * 32];
        while (__hip_atomic_load(p, __ATOMIC_RELAXED, __HIP_MEMORY_SCOPE_AGENT) < target) {}
    }
    __syncthreads();
}

// ---------------- persistent fused kernel ----------------
// blocks 0..63   ("B"): batch b; uak[b]+enc[b] LDS-resident. attention.
// blocks 64..95  ("G"): 16-col GRU slice; weights LDS-resident (swizzled); h in regs.
// blocks 96..255 ("L"): logits GEMM jobs, gated on G flags (observe-only: no
//                       new arrivals -> B/G handshake unchanged, no deadlock cycle).
// Flags per step t: G arrives 3t+1 (Wh) and 3t+3 (h_t); B arrives 3t+2 (ctx).
// L chunk c (steps 4c..4c+3) waits for all G flags >= 12c+12.
__global__ __launch_bounds__(512, 1) void coop_kernel(
    const float* __restrict__ uak, float* __restrict__ Whbuf,
    u16* __restrict__ xbuf, u16* __restrict__ Abf,
    const u16* __restrict__ h0bf, const u16* __restrict__ wihbf, const u16* __restrict__ whhbf,
    const u16* __restrict__ Wabf, const u16* __restrict__ Wobf,
    const float* __restrict__ enc,
    const float* __restrict__ va, const float* __restrict__ bv, const float* __restrict__ ba,
    const float* __restrict__ b_ih, const float* __restrict__ b_hh, const float* __restrict__ bo,
    const float* __restrict__ ehid, float* __restrict__ out, float* __restrict__ sumexp,
    unsigned* __restrict__ bar) {
    __shared__ __align__(16) char lds[147456];
    __shared__ float WhL[512];
    __shared__ float scL[64];
    __shared__ float vaL[512];

    const size_t HID_OFF = (size_t)Bsz * Tsz * Vsz;
    const size_t ATT_OFF = HID_OFF + (size_t)Bsz * Hsz;

    int tid = threadIdx.x, lane = tid & 63, wid = tid >> 6;
    int ln15 = lane & 15, hi = lane >> 4;
    int bx = blockIdx.x;

    unsigned* xbufU = (unsigned*)xbuf;
    unsigned* AbfU = (unsigned*)Abf;

    if (bx < 64) {
        // ================= B-blocks: attention =================
        int b = bx;
        u16* uakL = (u16*)lds;
        u16* encL = (u16*)(lds + 65536);
        for (int i = tid; i < Ssz * Hsz; i += 512) {
            uakL[i] = f2bf(uak[(size_t)b * Ssz * Hsz + i]);
            encL[i] = f2bf(enc[(size_t)b * Ssz * Hsz + i]);
        }
        vaL[tid] = va[tid];
        float bvv = bv[0];
        __syncthreads();

        for (int t = 0; t < Tsz; ++t) {
            pollflags(bar, 64, 32, 3u * t + 1u, tid);           // Wh ready
            WhL[tid] = Whbuf[(size_t)t * Bsz * Hsz + (size_t)b * 512 + tid];
            __syncthreads();
            for (int si = 0; si < 8; ++si) {
                int s = wid * 8 + si;
                float a = 0.f;
#pragma unroll
                for (int ji = 0; ji < 8; ++ji) {
                    int j = lane + ji * 64;
                    float x = WhL[j] + bf2f(uakL[s * 512 + j]);
                    a += tanh_fast(x) * vaL[j];
                }
                for (int off = 32; off; off >>= 1) a += __shfl_down(a, off);
                if (lane == 0) scL[s] = a + bvv;
            }
            __syncthreads();
            if (wid == 0) {
                float x = scL[lane];
                float mx = x;
                for (int off = 32; off; off >>= 1) mx = fmaxf(mx, __shfl_xor(mx, off));
                float e = __expf(x - mx);
                float sm = e;
                for (int off = 32; off; off >>= 1) sm += __shfl_xor(sm, off);
                float at = e / sm;
                scL[lane] = at;
                out[ATT_OFF + ((size_t)b * Tsz + t) * Ssz + lane] = at;
            }
            __syncthreads();
            float c = 0.f;
            for (int s = 0; s < Ssz; ++s)
                c += scL[s] * bf2f(encL[s * 512 + tid]);
            unsigned me = (unsigned)f2bf(c);
            unsigned other = __shfl_xor(me, 1);
            if ((tid & 1) == 0)
                st_u32(&xbufU[((size_t)t * Bsz + b) * 512 + 256 + (tid >> 1)], me | (other << 16));
            arrive(bar, bx, 3u * t + 2u, tid);                   // ctx ready
        }
    } else if (bx < 96) {
        // ================= G-blocks: Wh-MFMA + GRU =================
        int jbase = (bx - 64) * 16;
        for (int i = tid; i < 6144; i += 512) {
            int row = i >> 7, c16 = i & 127;
            int Rg = (row >> 4) * 512 + jbase + (row & 15);
            uint4 v = *(const uint4*)&wihbf[(size_t)Rg * 1024 + c16 * 8];
            *(uint4*)(lds + row * 2048 + ((c16 * 16) ^ ((row & 7) << 4))) = v;
        }
        for (int i = tid; i < 3072; i += 512) {
            int row = i >> 6, c16 = i & 63;
            int Rg = (row >> 4) * 512 + jbase + (row & 15);
            uint4 v = *(const uint4*)&whhbf[(size_t)Rg * 512 + c16 * 8];
            *(uint4*)(lds + 98304 + row * 1024 + ((c16 * 16) ^ ((row & 7) << 4))) = v;
        }
        const char* wih_l = lds;
        const char* whh_l = lds + 98304;
        int j = jbase + ln15;
        float ba_j = ba[j];
        float bir = b_ih[j] + b_hh[j];
        float biz = b_ih[512 + j] + b_hh[512 + j];
        float bin = b_ih[1024 + j];
        float bhn = b_hh[1024 + j];
        float hp0 = 0.f, hp1 = 0.f, hp2 = 0.f, hp3 = 0.f;
        if (wid < 4) {
            int m = wid;
            hp0 = ehid[(size_t)(m * 16 + hi * 4 + 0) * Hsz + j];
            hp1 = ehid[(size_t)(m * 16 + hi * 4 + 1) * Hsz + j];
            hp2 = ehid[(size_t)(m * 16 + hi * 4 + 2) * Hsz + j];
            hp3 = ehid[(size_t)(m * 16 + hi * 4 + 3) * Hsz + j];
        }
        int swz = (ln15 & 7) << 4;

        for (int t = 0; t < Tsz; ++t) {
            const u16* hbt = (t == 0) ? h0bf : (Abf + (size_t)(t - 1) * Bsz * Hsz);
            float* Whb = Whbuf + (size_t)t * Bsz * Hsz;
            pollflags(bar, 64, 32, 3u * t, tid);                 // all h_{t-1} written
            // ---- Wh = h_{t-1} @ Wa^T + ba ----
            if (wid < 4) {
                int m = wid;
                f32x4 acc = {};
#pragma unroll
                for (int k0 = 0; k0 < 16; ++k0) {
                    bf16x8 a = *(const bf16x8*)&hbt[(size_t)(m * 16 + ln15) * 512 + k0 * 32 + hi * 8];
                    bf16x8 bw = *(const bf16x8*)&Wabf[(size_t)(jbase + ln15) * 512 + k0 * 32 + hi * 8];
                    acc = __builtin_amdgcn_mfma_f32_16x16x32_bf16(a, bw, acc, 0, 0, 0);
                }
#pragma unroll
                for (int r = 0; r < 4; ++r)
                    st_f32(&Whb[(size_t)(m * 16 + hi * 4 + r) * 512 + j], acc[r] + ba_j);
            }
            arrive(bar, bx, 3u * t + 1u, tid);                   // Wh ready
            // ---- GRU prework (overlaps B's attention): wih*emb + whh*h ----
            f32x4 ar = {}, az = {}, ain = {}, ahn = {};
            if (wid < 4) {
                int m = wid;
#pragma unroll 8
                for (int k0 = 0; k0 < 16; ++k0) {
                    bf16x8 a = *(const bf16x8*)&xbuf[((size_t)t * Bsz + m * 16 + ln15) * 1024 + k0 * 32 + hi * 8];
                    int byteIn = k0 * 64 + hi * 16;
                    bf16x8 b0 = *(const bf16x8*)(wih_l + (0 + ln15) * 2048 + (byteIn ^ swz));
                    bf16x8 b1 = *(const bf16x8*)(wih_l + (16 + ln15) * 2048 + (byteIn ^ swz));
                    bf16x8 b2 = *(const bf16x8*)(wih_l + (32 + ln15) * 2048 + (byteIn ^ swz));
                    ar = __builtin_amdgcn_mfma_f32_16x16x32_bf16(a, b0, ar, 0, 0, 0);
                    az = __builtin_amdgcn_mfma_f32_16x16x32_bf16(a, b1, az, 0, 0, 0);
                    ain = __builtin_amdgcn_mfma_f32_16x16x32_bf16(a, b2, ain, 0, 0, 0);
                }
#pragma unroll 8
                for (int k0 = 0; k0 < 16; ++k0) {
                    bf16x8 a = *(const bf16x8*)&hbt[(size_t)(m * 16 + ln15) * 512 + k0 * 32 + hi * 8];
                    int byteIn = k0 * 64 + hi * 16;
                    bf16x8 b0 = *(const bf16x8*)(whh_l + (0 + ln15) * 1024 + (byteIn ^ swz));
                    bf16x8 b1 = *(const bf16x8*)(whh_l + (16 + ln15) * 1024 + (byteIn ^ swz));
                    bf16x8 b2 = *(const bf16x8*)(whh_l + (32 + ln15) * 1024 + (byteIn ^ swz));
                    ar = __builtin_amdgcn_mfma_f32_16x16x32_bf16(a, b0, ar, 0, 0, 0);
                    az = __builtin_amdgcn_mfma_f32_16x16x32_bf16(a, b1, az, 0, 0, 0);
                    ahn = __builtin_amdgcn_mfma_f32_16x16x32_bf16(a, b2, ahn, 0, 0, 0);
                }
            }
            // ---- per-wave ctx wait: wave m needs only batches 16m..16m+15 ----
            if (wid < 4) {
                unsigned* p = &bar[(wid * 16 + ln15) * 32];
                while (__hip_atomic_load(p, __ATOMIC_RELAXED, __HIP_MEMORY_SCOPE_AGENT) < 3u * t + 2u) {}
            }
            // ---- GRU critical: wih*ctx + gates ----
            if (wid < 4) {
                int m = wid;
#pragma unroll 8
                for (int k0 = 16; k0 < 32; ++k0) {
                    bf16x8 a = *(const bf16x8*)&xbuf[((size_t)t * Bsz + m * 16 + ln15) * 1024 + k0 * 32 + hi * 8];
                    int byteIn = k0 * 64 + hi * 16;
                    bf16x8 b0 = *(const bf16x8*)(wih_l + (0 + ln15) * 2048 + (byteIn ^ swz));
                    bf16x8 b1 = *(const bf16x8*)(wih_l + (16 + ln15) * 2048 + (byteIn ^ swz));
                    bf16x8 b2 = *(const bf16x8*)(wih_l + (32 + ln15) * 2048 + (byteIn ^ swz));
                    ar = __builtin_amdgcn_mfma_f32_16x16x32_bf16(a, b0, ar, 0, 0, 0);
                    az = __builtin_amdgcn_mfma_f32_16x16x32_bf16(a, b1, az, 0, 0, 0);
                    ain = __builtin_amdgcn_mfma_f32_16x16x32_bf16(a, b2, ain, 0, 0, 0);
                }
                float hpv[4] = {hp0, hp1, hp2, hp3};
#pragma unroll
                for (int r = 0; r < 4; ++r) {
                    int b = m * 16 + hi * 4 + r;
                    float rg = 1.f / (1.f + __expf(-(ar[r] + bir)));
                    float zg = 1.f / (1.f + __expf(-(az[r] + biz)));
                    float ng = tanh_fast(ain[r] + bin + rg * (ahn[r] + bhn));
                    float hv = (1.f - zg) * ng + zg * hpv[r];
                    hpv[r] = hv;
                    unsigned me = (unsigned)f2bf(hv);
                    unsigned other = __shfl_xor(me, 1);
                    if ((ln15 & 1) == 0)
                        st_u32(&AbfU[((size_t)t * Bsz + b) * 256 + (j >> 1)], me | (other << 16));
                    if (t == Tsz - 1) out[HID_OFF + (size_t)b * 512 + j] = hv;
                }
                hp0 = hpv[0]; hp1 = hpv[1]; hp2 = hpv[2]; hp3 = hpv[3];
            }
            arrive(bar, bx, 3u * t + 3u, tid);                   // h_t ready
        }
    } else {
        // ================= L-blocks: logits GEMM in the recurrence's shadow =========
        // chunk c = steps [4c, 4c+4): M-rows [256c, 256c+256) of Abf; 2 m-tiles x 250
        // n-tiles = 500 jobs/chunk, 4000 total, grid-strided over 160 blocks.
        int lb = bx - 96;
        u16* As = (u16*)lds;             // 128x32 bf16 = 8 KB
        u16* Bs = (u16*)(lds + 8192);
        int wm = wid & 1, wn = wid >> 1; // 2 x 4 waves -> wave tile 64x32
        int polled_c = -1;
        for (int job = lb; job < 4000; job += NLBLK) {
            int c = job / 500, idx = job % 500;
            int mt = idx / 250, nt = idx % 250;
            if (c != polled_c) {         // block-uniform condition
                pollflags(bar, 64, 32, 12u * c + 12u, tid);  // h ready through step 4c+3
                polled_c = c;
            }
            int m0 = c * 256 + mt * 128, n0 = nt * 128;
            f32x4 acc[4][2] = {};
            for (int k0 = 0; k0 < 512; k0 += 32) {
                int r = tid >> 2, c8 = (tid & 3) * 8;
                GLOAD_LDS16(&Abf[(size_t)(m0 + r) * 512 + k0 + c8], (char*)As + wid * 1024);
                GLOAD_LDS16(&Wobf[(size_t)(n0 + r) * 512 + k0 + c8], (char*)Bs + wid * 1024);
                __syncthreads();
                bf16x8 av[4], bvv[2];
                for (int mi = 0; mi < 4; ++mi)
                    av[mi] = *(const bf16x8*)&As[(wm * 64 + mi * 16 + ln15) * 32 + hi * 8];
                for (int ni = 0; ni < 2; ++ni)
                    bvv[ni] = *(const bf16x8*)&Bs[(wn * 32 + ni * 16 + ln15) * 32 + hi * 8];
                for (int mi = 0; mi < 4; ++mi)
                    for (int ni = 0; ni < 2; ++ni)
                        acc[mi][ni] = __builtin_amdgcn_mfma_f32_16x16x32_bf16(av[mi], bvv[ni], acc[mi][ni], 0, 0, 0);
                __syncthreads();
            }
            float rowpart[4][4];
            for (int mi = 0; mi < 4; ++mi)
                for (int r = 0; r < 4; ++r) rowpart[mi][r] = 0.f;
            for (int mi = 0; mi < 4; ++mi)
                for (int ni = 0; ni < 2; ++ni) {
                    int n = n0 + wn * 32 + ni * 16 + ln15;
                    float bb = bo[n];
                    for (int r = 0; r < 4; ++r) {
                        int m = m0 + wm * 64 + mi * 16 + hi * 4 + r;
                        int t = m >> 6, b = m & 63;
                        float val = acc[mi][ni][r] + bb;
                        out[((size_t)(b * Tsz + t)) * Vsz + n] = val;
                        rowpart[mi][r] += __expf(val);
                    }
                }
            for (int mi = 0; mi < 4; ++mi)
                for (int r = 0; r < 4; ++r) {
                    float v = rowpart[mi][r];
                    v += __shfl_xor(v, 1);
                    v += __shfl_xor(v, 2);
                    v += __shfl_xor(v, 4);
                    v += __shfl_xor(v, 8);
                    if (ln15 == 0) {
                        int m = m0 + wm * 64 + mi * 16 + hi * 4 + r;
                        atomicAdd(&sumexp[(m & 63) * Tsz + (m >> 6)], v);
                    }
                }
        }
    }
}

// ---------------- log-softmax subtract (uses fused sumexp) ----------------
__global__ void sub_kernel(float* __restrict__ out, const float* __restrict__ sumexp) {
    const int total4 = (Bsz * Tsz * Vsz) / 4;
    float4* o4 = (float4*)out;
    for (int i = blockIdx.x * blockDim.x + threadIdx.x; i < total4; i += gridDim.x * blockDim.x) {
        float l = __logf(sumexp[i / (Vsz / 4)]);
        float4 v = o4[i];
        v.x -= l; v.y -= l; v.z -= l; v.w -= l;
        o4[i] = v;
    }
}

extern "C" void kernel_launch(void* const* d_in, const int* in_sizes, int n_in,
                              void* d_out, int out_size, void* d_ws, size_t ws_size,
                              hipStream_t stream) {
    const float* enc   = (const float*)d_in[0];
    const float* ehid  = (const float*)d_in[1];
    const int*   target= (const int*)d_in[2];
    const float* emb   = (const float*)d_in[3];
    const float* Wa    = (const float*)d_in[4];
    const float* ba    = (const float*)d_in[5];
    const float* Ua    = (const float*)d_in[6];
    const float* bu    = (const float*)d_in[7];
    const float* va    = (const float*)d_in[8];
    const float* bv    = (const float*)d_in[9];
    const float* w_ih  = (const float*)d_in[10];
    const float* b_ih  = (const float*)d_in[11];
    const float* w_hh  = (const float*)d_in[12];
    const float* b_hh  = (const float*)d_in[13];
    const float* Wo    = (const float*)d_in[14];
    const float* bo    = (const float*)d_in[15];
    float* out = (float*)d_out;

    char* w = (char*)d_ws;
    float* uak   = (float*)w; w += (size_t)4096 * 512 * 4;            // 8 MB
    float* Whbuf = (float*)w; w += (size_t)Tsz * Bsz * Hsz * 4;       // 4 MB
    float* sumexp= (float*)w; w += 8192;
    unsigned* bar= (unsigned*)w; w += 96 * 128;                       // 96 x 128B flag slots
    u16* xbuf    = (u16*)w;   w += (size_t)Tsz * Bsz * 1024 * 2;      // 4 MB
    u16* Abf     = (u16*)w;   w += (size_t)Tsz * Bsz * Hsz * 2;       // 2 MB
    u16* h0bf    = (u16*)w;   w += (size_t)Bsz * Hsz * 2;
    u16* Wabf    = (u16*)w;   w += (size_t)Hsz * Hsz * 2;
    u16* encbf   = (u16*)w;   w += (size_t)4096 * 512 * 2;
    u16* Uabf    = (u16*)w;   w += (size_t)Hsz * Hsz * 2;
    u16* wihbf   = (u16*)w;   w += (size_t)1536 * 1024 * 2;
    u16* whhbf   = (u16*)w;   w += (size_t)1536 * 512 * 2;
    u16* Wobf    = (u16*)w;   w += (size_t)Vsz * 512 * 2;

    prep_kernel<<<2048, 256, 0, stream>>>(enc, Ua, Wa, w_ih, w_hh, Wo, ehid,
                                          encbf, Uabf, Wabf, wihbf, whhbf, Wobf, h0bf);
    embed_kernel<<<1024, 256, 0, stream>>>(target, emb, xbuf);

    // Ua_keys = enc @ Ua.T + bu   (M=4096, N=512, K=512)
    gemm_bt<<<dim3(32, 4), 256, 0, stream>>>(encbf, Uabf, bu, uak, 4096, 512, 512);

    // bar region is 96 slots x 128 BYTES. (Round-4 lesson: memset exactly this.)
    hipMemsetAsync(bar, 0, 96 * 128, stream);
    hipMemsetAsync(sumexp, 0, 2048 * 4, stream);

    // recurrence + logits GEMM fused: 256 blocks = 1 per CU, all co-resident
    coop_kernel<<<NTOT, 512, 0, stream>>>(uak, Whbuf, xbuf, Abf, h0bf, wihbf, whhbf,
                                          Wabf, Wobf, enc, va, bv, ba, b_ih, b_hh, bo,
                                          ehid, out, sumexp, bar);

    sub_kernel<<<2048, 256, 0, stream>>>(out, sumexp);
}

// Round 7
// 1010.853 us; speedup vs baseline: 1.0497x; 1.0497x over previous
//
#include <hip/hip_runtime.h>

typedef unsigned short u16;
typedef __bf16 bf16x8 __attribute__((ext_vector_type(8)));
typedef float f32x4 __attribute__((ext_vector_type(4)));

#define Bsz 64
#define Ssz 64
#define Tsz 32
#define Hsz 512
#define Vsz 32000
#define NLBLK 160    // logits-GEMM blocks
#define NTOT 256     // 1 block per CU

static __device__ inline u16 f2bf(float f) {
    union { float f; unsigned u; } v; v.f = f;
    unsigned u = v.u;
    unsigned r = (u + 0x7FFFu + ((u >> 16) & 1u)) >> 16;
    return (u16)r;
}
static __device__ inline float bf2f(u16 v) {
    union { unsigned u; float f; } x; x.u = ((unsigned)v) << 16; return x.f;
}
static __device__ inline float tanh_fast(float x) {
    float e = __expf(2.f * x);
    return 1.f - 2.f / (e + 1.f);
}
// agent-scope write-through stores (sc1) — reach the IC coherence point
static __device__ inline void st_f32(float* p, float v) {
    __hip_atomic_store(p, v, __ATOMIC_RELAXED, __HIP_MEMORY_SCOPE_AGENT);
}
static __device__ inline void st_u32(unsigned* p, unsigned v) {
    __hip_atomic_store(p, v, __ATOMIC_RELAXED, __HIP_MEMORY_SCOPE_AGENT);
}

// direct-to-LDS 16B async copy (wave-uniform LDS base + lane*16 scatter)
#define GLOAD_LDS16(g, l) \
    __builtin_amdgcn_global_load_lds((const __attribute__((address_space(1))) void*)(g), \
                                     (__attribute__((address_space(3))) void*)(l), 16, 0, 0)

// ---------------- fused f32 -> bf16 weight prep ----------------
// WaTp: transposed + pair-packed Wa for B's GEMV:
//   WaTp[kk*512 + j] = pack(bf16(Wa[j][2kk]), bf16(Wa[j][2kk+1])), kk in [0,256)
__global__ void prep_kernel(const float* __restrict__ enc, const float* __restrict__ Ua,
                            const float* __restrict__ Wa, const float* __restrict__ wih,
                            const float* __restrict__ whh, const float* __restrict__ Wo,
                            const float* __restrict__ ehid,
                            u16* __restrict__ encbf, u16* __restrict__ Uabf,
                            unsigned* __restrict__ WaTp, u16* __restrict__ wihbf,
                            u16* __restrict__ whhbf, u16* __restrict__ Wobf,
                            u16* __restrict__ h0bf) {
    const int n0 = 2097152, n1 = 262144, n2 = 131072, n3 = 1572864, n4 = 786432, n5 = 16384000, n6 = 32768;
    const int total = n0 + n1 + n2 + n3 + n4 + n5 + n6;
    for (int i = blockIdx.x * blockDim.x + threadIdx.x; i < total; i += gridDim.x * blockDim.x) {
        int j = i;
        if (j < n0) { encbf[j] = f2bf(enc[j]); continue; } j -= n0;
        if (j < n1) { Uabf[j] = f2bf(Ua[j]); continue; } j -= n1;
        if (j < n2) {
            int kk = j >> 9, c = j & 511;
            unsigned lo = f2bf(Wa[(size_t)c * 512 + 2 * kk]);
            unsigned hi = f2bf(Wa[(size_t)c * 512 + 2 * kk + 1]);
            WaTp[j] = lo | (hi << 16); continue;
        } j -= n2;
        if (j < n3) { wihbf[j] = f2bf(wih[j]); continue; } j -= n3;
        if (j < n4) { whhbf[j] = f2bf(whh[j]); continue; } j -= n4;
        if (j < n5) { Wobf[j] = f2bf(Wo[j]); continue; } j -= n5;
        h0bf[j] = f2bf(ehid[j]);
    }
}

// ---------------- embedding gather into xbuf[t][b][0:512] (bf16) ----------------
__global__ void embed_kernel(const int* __restrict__ target, const float* __restrict__ emb,
                             u16* __restrict__ xbuf) {
    int n = Tsz * Bsz * Hsz;
    for (int i = blockIdx.x * blockDim.x + threadIdx.x; i < n; i += gridDim.x * blockDim.x) {
        int t = i / (Bsz * Hsz);
        int rem = i % (Bsz * Hsz);
        int b = rem / Hsz, k = rem % Hsz;
        int id = (t == 0) ? 0 : target[b * Tsz + (t - 1)];
        xbuf[((size_t)t * Bsz + b) * 1024 + k] = f2bf(emb[(size_t)id * Hsz + k]);
    }
}

// ---------------- bf16 MFMA GEMM (Ua_keys only) ----------------
__global__ __launch_bounds__(256) void gemm_bt(const u16* __restrict__ A, const u16* __restrict__ Bw,
                                               const float* __restrict__ bias, float* __restrict__ out,
                                               int M, int N, int K) {
    __shared__ __align__(16) u16 As[128 * 32];
    __shared__ __align__(16) u16 Bs[128 * 32];
    int m0 = blockIdx.x * 128, n0 = blockIdx.y * 128;
    int tid = threadIdx.x, lane = tid & 63, wid = tid >> 6;
    int wm = wid & 1, wn = wid >> 1;
    f32x4 acc[4][4] = {};
    for (int k0 = 0; k0 < K; k0 += 32) {
        int e0 = wid * 64 + lane;
        int e1 = e0 + 256;
        GLOAD_LDS16(&A[(size_t)(m0 + (e0 >> 2)) * K + k0 + (e0 & 3) * 8], (char*)As + wid * 1024);
        GLOAD_LDS16(&A[(size_t)(m0 + (e1 >> 2)) * K + k0 + (e1 & 3) * 8], (char*)As + 4096 + wid * 1024);
        GLOAD_LDS16(&Bw[(size_t)(n0 + (e0 >> 2)) * K + k0 + (e0 & 3) * 8], (char*)Bs + wid * 1024);
        GLOAD_LDS16(&Bw[(size_t)(n0 + (e1 >> 2)) * K + k0 + (e1 & 3) * 8], (char*)Bs + 4096 + wid * 1024);
        __syncthreads();
        bf16x8 av[4], bvv[4];
        for (int mi = 0; mi < 4; ++mi)
            av[mi] = *(const bf16x8*)&As[(wm * 64 + mi * 16 + (lane & 15)) * 32 + (lane >> 4) * 8];
        for (int ni = 0; ni < 4; ++ni)
            bvv[ni] = *(const bf16x8*)&Bs[(wn * 64 + ni * 16 + (lane & 15)) * 32 + (lane >> 4) * 8];
        for (int mi = 0; mi < 4; ++mi)
            for (int ni = 0; ni < 4; ++ni)
                acc[mi][ni] = __builtin_amdgcn_mfma_f32_16x16x32_bf16(av[mi], bvv[ni], acc[mi][ni], 0, 0, 0);
        __syncthreads();
    }
    for (int mi = 0; mi < 4; ++mi)
        for (int ni = 0; ni < 4; ++ni) {
            int n = n0 + wn * 64 + ni * 16 + (lane & 15);
            float bb = bias[n];
            for (int r = 0; r < 4; ++r) {
                int m = m0 + wm * 64 + mi * 16 + (lane >> 4) * 4 + r;
                out[(size_t)m * N + n] = acc[mi][ni][r] + bb;
            }
        }
}

// ---------------- flag-array sync ----------------
static __device__ inline void arrive(unsigned* bar, int slot, unsigned val, int tid) {
    asm volatile("s_waitcnt vmcnt(0)" ::: "memory");
    __syncthreads();
    if (tid == 0) st_u32(&bar[slot * 32], val);
}
static __device__ inline void pollflags(unsigned* bar, int base, int n, unsigned target, int tid) {
    if (tid < n) {
        unsigned* p = &bar[(base + tid) * 32];
        while (__hip_atomic_load(p, __ATOMIC_RELAXED, __HIP_MEMORY_SCOPE_AGENT) < target) {}
    }
    __syncthreads();
}
static __device__ inline void pollflags_sleep(unsigned* bar, int base, int n, unsigned target, int tid) {
    if (tid < n) {
        unsigned* p = &bar[(base + tid) * 32];
        while (__hip_atomic_load(p, __ATOMIC_RELAXED, __HIP_MEMORY_SCOPE_AGENT) < target)
            asm volatile("s_sleep 8");
    }
    __syncthreads();
}

static __device__ inline void l_stage(const u16* __restrict__ Abf, const u16* __restrict__ Wobf,
                                      int m0, int n0, int k0, char* As, char* Bs, int wid, int lane) {
    int e0 = wid * 64 + lane;
    int r = e0 >> 2, c8 = (e0 & 3) * 8;
    GLOAD_LDS16(&Abf[(size_t)(m0 + r) * 512 + k0 + c8], As + wid * 1024);
    GLOAD_LDS16(&Wobf[(size_t)(n0 + r) * 512 + k0 + c8], Bs + wid * 1024);
    GLOAD_LDS16(&Wobf[(size_t)(n0 + 128 + r) * 512 + k0 + c8], Bs + 8192 + wid * 1024);
}

// ---------------- persistent fused kernel ----------------
// blocks 0..63   ("B"): batch b; uak[b]+enc[b] LDS-resident. Wh-GEMV + attention.
// blocks 64..95  ("G"): 16-col GRU slice; weights LDS-resident (swizzled); h in regs.
// blocks 96..255 ("L"): logits GEMM 128x256 tiles, dbuf + counted vmcnt, gated on G flags.
// Flags: B slot b arrives t+1 after ctx_t; G slot arrives t+1 after h_t.
// B step t polls G>=t (h_{t-1}); G preworks (own h + emb), per-wave polls B>=t+1 (ctx);
// L chunk mt (rows 128mt..128mt+127 = steps 2mt,2mt+1) polls G>=2mt+2.
__global__ __launch_bounds__(512, 1) void coop_kernel(
    const float* __restrict__ uak,
    u16* __restrict__ xbuf, u16* __restrict__ Abf,
    const u16* __restrict__ h0bf, const u16* __restrict__ wihbf, const u16* __restrict__ whhbf,
    const unsigned* __restrict__ WaTp, const u16* __restrict__ Wobf,
    const float* __restrict__ enc,
    const float* __restrict__ va, const float* __restrict__ bv, const float* __restrict__ ba,
    const float* __restrict__ b_ih, const float* __restrict__ b_hh, const float* __restrict__ bo,
    const float* __restrict__ ehid, float* __restrict__ out, float* __restrict__ sumexp,
    unsigned* __restrict__ bar) {
    __shared__ __align__(16) char lds[147456];
    __shared__ float WhL[512];
    __shared__ float scL[64];
    __shared__ float vaL[512];
    __shared__ float hL[512];

    const size_t HID_OFF = (size_t)Bsz * Tsz * Vsz;
    const size_t ATT_OFF = HID_OFF + (size_t)Bsz * Hsz;

    int tid = threadIdx.x, lane = tid & 63, wid = tid >> 6;
    int ln15 = lane & 15, hi = lane >> 4;
    int bx = blockIdx.x;

    unsigned* xbufU = (unsigned*)xbuf;
    unsigned* AbfU = (unsigned*)Abf;

    if (bx < 64) {
        // ================= B-blocks: Wh-GEMV + attention =================
        int b = bx;
        u16* uakL = (u16*)lds;
        u16* encL = (u16*)(lds + 65536);
        for (int i = tid; i < Ssz * Hsz; i += 512) {
            uakL[i] = f2bf(uak[(size_t)b * Ssz * Hsz + i]);
            encL[i] = f2bf(enc[(size_t)b * Ssz * Hsz + i]);
        }
        vaL[tid] = va[tid];
        float bvv = bv[0];
        float ba_t = ba[tid];
        __syncthreads();

        for (int t = 0; t < Tsz; ++t) {
            if (t) pollflags(bar, 64, 32, (unsigned)t, tid);     // h_{t-1} ready
            {
                const u16* hrow = t ? (Abf + ((size_t)(t - 1) * Bsz + b) * 512)
                                    : (h0bf + (size_t)b * 512);
                hL[tid] = bf2f(hrow[tid]);
            }
            __syncthreads();
            // Wh[j=tid] = sum_k h[k] * Wa[j][k] + ba[j]  via packed WaTp
            {
                float acc = ba_t;
                const float4* hL4 = (const float4*)hL;
#pragma unroll 8
                for (int kk4 = 0; kk4 < 128; ++kk4) {
                    float4 hv = hL4[kk4];
                    unsigned w0 = WaTp[(size_t)(2 * kk4) * 512 + tid];
                    unsigned w1 = WaTp[(size_t)(2 * kk4 + 1) * 512 + tid];
                    acc += hv.x * bf2f((u16)w0) + hv.y * bf2f((u16)(w0 >> 16))
                         + hv.z * bf2f((u16)w1) + hv.w * bf2f((u16)(w1 >> 16));
                }
                WhL[tid] = acc;
            }
            __syncthreads();
            for (int si = 0; si < 8; ++si) {
                int s = wid * 8 + si;
                float a = 0.f;
#pragma unroll
                for (int ji = 0; ji < 8; ++ji) {
                    int j = lane + ji * 64;
                    float x = WhL[j] + bf2f(uakL[s * 512 + j]);
                    a += tanh_fast(x) * vaL[j];
                }
                for (int off = 32; off; off >>= 1) a += __shfl_down(a, off);
                if (lane == 0) scL[s] = a + bvv;
            }
            __syncthreads();
            if (wid == 0) {
                float x = scL[lane];
                float mx = x;
                for (int off = 32; off; off >>= 1) mx = fmaxf(mx, __shfl_xor(mx, off));
                float e = __expf(x - mx);
                float sm = e;
                for (int off = 32; off; off >>= 1) sm += __shfl_xor(sm, off);
                float at = e / sm;
                scL[lane] = at;
                out[ATT_OFF + ((size_t)b * Tsz + t) * Ssz + lane] = at;
            }
            __syncthreads();
            float c = 0.f;
            for (int s = 0; s < Ssz; ++s)
                c += scL[s] * bf2f(encL[s * 512 + tid]);
            unsigned me = (unsigned)f2bf(c);
            unsigned other = __shfl_xor(me, 1);
            if ((tid & 1) == 0)
                st_u32(&xbufU[((size_t)t * Bsz + b) * 512 + 256 + (tid >> 1)], me | (other << 16));
            arrive(bar, bx, (unsigned)(t + 1), tid);             // ctx ready
        }
    } else if (bx < 96) {
        // ================= G-blocks: GRU =================
        int jbase = (bx - 64) * 16;
        for (int i = tid; i < 6144; i += 512) {
            int row = i >> 7, c16 = i & 127;
            int Rg = (row >> 4) * 512 + jbase + (row & 15);
            uint4 v = *(const uint4*)&wihbf[(size_t)Rg * 1024 + c16 * 8];
            *(uint4*)(lds + row * 2048 + ((c16 * 16) ^ ((row & 7) << 4))) = v;
        }
        for (int i = tid; i < 3072; i += 512) {
            int row = i >> 6, c16 = i & 63;
            int Rg = (row >> 4) * 512 + jbase + (row & 15);
            uint4 v = *(const uint4*)&whhbf[(size_t)Rg * 512 + c16 * 8];
            *(uint4*)(lds + 98304 + row * 1024 + ((c16 * 16) ^ ((row & 7) << 4))) = v;
        }
        const char* wih_l = lds;
        const char* whh_l = lds + 98304;
        int j = jbase + ln15;
        float bir = b_ih[j] + b_hh[j];
        float biz = b_ih[512 + j] + b_hh[512 + j];
        float bin = b_ih[1024 + j];
        float bhn = b_hh[1024 + j];
        float hp0 = 0.f, hp1 = 0.f, hp2 = 0.f, hp3 = 0.f;
        if (wid < 4) {
            int m = wid;
            hp0 = ehid[(size_t)(m * 16 + hi * 4 + 0) * Hsz + j];
            hp1 = ehid[(size_t)(m * 16 + hi * 4 + 1) * Hsz + j];
            hp2 = ehid[(size_t)(m * 16 + hi * 4 + 2) * Hsz + j];
            hp3 = ehid[(size_t)(m * 16 + hi * 4 + 3) * Hsz + j];
        }
        int swz = (ln15 & 7) << 4;
        __syncthreads();

        for (int t = 0; t < Tsz; ++t) {
            const u16* hbt = t ? (Abf + (size_t)(t - 1) * Bsz * Hsz) : h0bf;
            if (t) pollflags(bar, 64, 32, (unsigned)t, tid);     // peers' h_{t-1}
            // ---- prework (overlaps B's window): wih*emb + whh*h_{t-1} ----
            f32x4 ar = {}, az = {}, ain = {}, ahn = {};
            if (wid < 4) {
                int m = wid;
#pragma unroll 8
                for (int k0 = 0; k0 < 16; ++k0) {
                    bf16x8 a = *(const bf16x8*)&xbuf[((size_t)t * Bsz + m * 16 + ln15) * 1024 + k0 * 32 + hi * 8];
                    int byteIn = k0 * 64 + hi * 16;
                    bf16x8 b0 = *(const bf16x8*)(wih_l + (0 + ln15) * 2048 + (byteIn ^ swz));
                    bf16x8 b1 = *(const bf16x8*)(wih_l + (16 + ln15) * 2048 + (byteIn ^ swz));
                    bf16x8 b2 = *(const bf16x8*)(wih_l + (32 + ln15) * 2048 + (byteIn ^ swz));
                    ar = __builtin_amdgcn_mfma_f32_16x16x32_bf16(a, b0, ar, 0, 0, 0);
                    az = __builtin_amdgcn_mfma_f32_16x16x32_bf16(a, b1, az, 0, 0, 0);
                    ain = __builtin_amdgcn_mfma_f32_16x16x32_bf16(a, b2, ain, 0, 0, 0);
                }
#pragma unroll 8
                for (int k0 = 0; k0 < 16; ++k0) {
                    bf16x8 a = *(const bf16x8*)&hbt[(size_t)(m * 16 + ln15) * 512 + k0 * 32 + hi * 8];
                    int byteIn = k0 * 64 + hi * 16;
                    bf16x8 b0 = *(const bf16x8*)(whh_l + (0 + ln15) * 1024 + (byteIn ^ swz));
                    bf16x8 b1 = *(const bf16x8*)(whh_l + (16 + ln15) * 1024 + (byteIn ^ swz));
                    bf16x8 b2 = *(const bf16x8*)(whh_l + (32 + ln15) * 1024 + (byteIn ^ swz));
                    ar = __builtin_amdgcn_mfma_f32_16x16x32_bf16(a, b0, ar, 0, 0, 0);
                    az = __builtin_amdgcn_mfma_f32_16x16x32_bf16(a, b1, az, 0, 0, 0);
                    ahn = __builtin_amdgcn_mfma_f32_16x16x32_bf16(a, b2, ahn, 0, 0, 0);
                }
                // per-wave ctx wait: wave m needs only batches 16m..16m+15
                unsigned* p = &bar[(wid * 16 + ln15) * 32];
                while (__hip_atomic_load(p, __ATOMIC_RELAXED, __HIP_MEMORY_SCOPE_AGENT) < (unsigned)(t + 1)) {}
                // ---- critical: wih*ctx + gates ----
#pragma unroll 8
                for (int k0 = 16; k0 < 32; ++k0) {
                    bf16x8 a = *(const bf16x8*)&xbuf[((size_t)t * Bsz + m * 16 + ln15) * 1024 + k0 * 32 + hi * 8];
                    int byteIn = k0 * 64 + hi * 16;
                    bf16x8 b0 = *(const bf16x8*)(wih_l + (0 + ln15) * 2048 + (byteIn ^ swz));
                    bf16x8 b1 = *(const bf16x8*)(wih_l + (16 + ln15) * 2048 + (byteIn ^ swz));
                    bf16x8 b2 = *(const bf16x8*)(wih_l + (32 + ln15) * 2048 + (byteIn ^ swz));
                    ar = __builtin_amdgcn_mfma_f32_16x16x32_bf16(a, b0, ar, 0, 0, 0);
                    az = __builtin_amdgcn_mfma_f32_16x16x32_bf16(a, b1, az, 0, 0, 0);
                    ain = __builtin_amdgcn_mfma_f32_16x16x32_bf16(a, b2, ain, 0, 0, 0);
                }
                float hpv[4] = {hp0, hp1, hp2, hp3};
#pragma unroll
                for (int r = 0; r < 4; ++r) {
                    int b = m * 16 + hi * 4 + r;
                    float rg = 1.f / (1.f + __expf(-(ar[r] + bir)));
                    float zg = 1.f / (1.f + __expf(-(az[r] + biz)));
                    float ng = tanh_fast(ain[r] + bin + rg * (ahn[r] + bhn));
                    float hv = (1.f - zg) * ng + zg * hpv[r];
                    hpv[r] = hv;
                    unsigned me = (unsigned)f2bf(hv);
                    unsigned other = __shfl_xor(me, 1);
                    if ((ln15 & 1) == 0)
                        st_u32(&AbfU[((size_t)t * Bsz + b) * 256 + (j >> 1)], me | (other << 16));
                    if (t == Tsz - 1) out[HID_OFF + (size_t)b * 512 + j] = hv;
                }
                hp0 = hpv[0]; hp1 = hpv[1]; hp2 = hpv[2]; hp3 = hpv[3];
            }
            arrive(bar, bx, (unsigned)(t + 1), tid);             // h_t ready
        }
    } else {
        // ================= L-blocks: logits GEMM (128x256, dbuf, counted vmcnt) ======
        int lb = bx - 96;
        char* As0 = lds;                  // 8 KB
        char* Bs0 = lds + 8192;           // 16 KB
        char* As1 = lds + 24576;
        char* Bs1 = lds + 32768;
        int wm = wid & 1, wn = wid >> 1;  // 2(M) x 4(N) waves -> wave tile 64x64
        int polled_mt = -1;
        for (int job = lb; job < 2000; job += NLBLK) {
            int mt = job / 125, nt = job % 125;
            if (mt != polled_mt) {
                pollflags_sleep(bar, 64, 32, (unsigned)(2 * mt + 2), tid);
                polled_mt = mt;
            }
            int m0 = mt * 128, n0 = nt * 256;
            f32x4 acc[4][4] = {};
            l_stage(Abf, Wobf, m0, n0, 0, As0, Bs0, wid, lane);
#pragma unroll 2
            for (int ks = 0; ks < 16; ++ks) {
                const u16* As = (const u16*)((ks & 1) ? As1 : As0);
                const u16* Bs = (const u16*)((ks & 1) ? Bs1 : Bs0);
                if (ks < 15) {
                    l_stage(Abf, Wobf, m0, n0, (ks + 1) * 32,
                            (ks & 1) ? As0 : As1, (ks & 1) ? Bs0 : Bs1, wid, lane);
                    asm volatile("s_waitcnt vmcnt(3)" ::: "memory");
                } else {
                    asm volatile("s_waitcnt vmcnt(0)" ::: "memory");
                }
                __builtin_amdgcn_s_barrier();
                bf16x8 av[4], bvv[4];
                for (int mi = 0; mi < 4; ++mi)
                    av[mi] = *(const bf16x8*)&As[(wm * 64 + mi * 16 + ln15) * 32 + hi * 8];
                for (int ni = 0; ni < 4; ++ni)
                    bvv[ni] = *(const bf16x8*)&Bs[(wn * 64 + ni * 16 + ln15) * 32 + hi * 8];
                for (int mi = 0; mi < 4; ++mi)
                    for (int ni = 0; ni < 4; ++ni)
                        acc[mi][ni] = __builtin_amdgcn_mfma_f32_16x16x32_bf16(av[mi], bvv[ni], acc[mi][ni], 0, 0, 0);
                asm volatile("s_waitcnt lgkmcnt(0)" ::: "memory");
                __builtin_amdgcn_s_barrier();
            }
            float rowpart[4][4];
            for (int mi = 0; mi < 4; ++mi)
                for (int r = 0; r < 4; ++r) rowpart[mi][r] = 0.f;
            for (int mi = 0; mi < 4; ++mi)
                for (int ni = 0; ni < 4; ++ni) {
                    int n = n0 + wn * 64 + ni * 16 + ln15;
                    float bb = bo[n];
                    for (int r = 0; r < 4; ++r) {
                        int m = m0 + wm * 64 + mi * 16 + hi * 4 + r;
                        int t = m >> 6, b = m & 63;
                        float val = acc[mi][ni][r] + bb;
                        out[((size_t)(b * Tsz + t)) * Vsz + n] = val;
                        rowpart[mi][r] += __expf(val);
                    }
                }
            for (int mi = 0; mi < 4; ++mi)
                for (int r = 0; r < 4; ++r) {
                    float v = rowpart[mi][r];
                    v += __shfl_xor(v, 1);
                    v += __shfl_xor(v, 2);
                    v += __shfl_xor(v, 4);
                    v += __shfl_xor(v, 8);
                    if (ln15 == 0) {
                        int m = m0 + wm * 64 + mi * 16 + hi * 4 + r;
                        atomicAdd(&sumexp[(m & 63) * Tsz + (m >> 6)], v);
                    }
                }
        }
    }
}

// ---------------- log-softmax subtract ----------------
__global__ void sub_kernel(float* __restrict__ out, const float* __restrict__ sumexp) {
    const int total4 = (Bsz * Tsz * Vsz) / 4;
    float4* o4 = (float4*)out;
    for (int i = blockIdx.x * blockDim.x + threadIdx.x; i < total4; i += gridDim.x * blockDim.x) {
        float l = __logf(sumexp[i / (Vsz / 4)]);
        float4 v = o4[i];
        v.x -= l; v.y -= l; v.z -= l; v.w -= l;
        o4[i] = v;
    }
}

extern "C" void kernel_launch(void* const* d_in, const int* in_sizes, int n_in,
                              void* d_out, int out_size, void* d_ws, size_t ws_size,
                              hipStream_t stream) {
    const float* enc   = (const float*)d_in[0];
    const float* ehid  = (const float*)d_in[1];
    const int*   target= (const int*)d_in[2];
    const float* emb   = (const float*)d_in[3];
    const float* Wa    = (const float*)d_in[4];
    const float* ba    = (const float*)d_in[5];
    const float* Ua    = (const float*)d_in[6];
    const float* bu    = (const float*)d_in[7];
    const float* va    = (const float*)d_in[8];
    const float* bv    = (const float*)d_in[9];
    const float* w_ih  = (const float*)d_in[10];
    const float* b_ih  = (const float*)d_in[11];
    const float* w_hh  = (const float*)d_in[12];
    const float* b_hh  = (const float*)d_in[13];
    const float* Wo    = (const float*)d_in[14];
    const float* bo    = (const float*)d_in[15];
    float* out = (float*)d_out;

    char* w = (char*)d_ws;
    float* uak    = (float*)w; w += (size_t)4096 * 512 * 4;           // 8 MB
    float* sumexp = (float*)w; w += 8192;
    unsigned* bar = (unsigned*)w; w += 96 * 128;                      // 96 x 128B flag slots
    u16* xbuf     = (u16*)w;   w += (size_t)Tsz * Bsz * 1024 * 2;     // 4 MB
    u16* Abf      = (u16*)w;   w += (size_t)Tsz * Bsz * Hsz * 2;      // 2 MB
    u16* h0bf     = (u16*)w;   w += (size_t)Bsz * Hsz * 2;
    unsigned* WaTp= (unsigned*)w; w += (size_t)131072 * 4;            // 512 KB
    u16* encbf    = (u16*)w;   w += (size_t)4096 * 512 * 2;
    u16* Uabf     = (u16*)w;   w += (size_t)Hsz * Hsz * 2;
    u16* wihbf    = (u16*)w;   w += (size_t)1536 * 1024 * 2;
    u16* whhbf    = (u16*)w;   w += (size_t)1536 * 512 * 2;
    u16* Wobf     = (u16*)w;   w += (size_t)Vsz * 512 * 2;

    prep_kernel<<<2048, 256, 0, stream>>>(enc, Ua, Wa, w_ih, w_hh, Wo, ehid,
                                          encbf, Uabf, WaTp, wihbf, whhbf, Wobf, h0bf);
    embed_kernel<<<1024, 256, 0, stream>>>(target, emb, xbuf);

    // Ua_keys = enc @ Ua.T + bu   (M=4096, N=512, K=512)
    gemm_bt<<<dim3(32, 4), 256, 0, stream>>>(encbf, Uabf, bu, uak, 4096, 512, 512);

    hipMemsetAsync(bar, 0, 96 * 128, stream);        // exactly the flag region
    hipMemsetAsync(sumexp, 0, 2048 * 4, stream);

    coop_kernel<<<NTOT, 512, 0, stream>>>(uak, xbuf, Abf, h0bf, wihbf, whhbf,
                                          WaTp, Wobf, enc, va, bv, ba, b_ih, b_hh, bo,
                                          ehid, out, sumexp, bar);

    sub_kernel<<<2048, 256, 0, stream>>>(out, sumexp);
}

// Round 8
// 976.440 us; speedup vs baseline: 1.0867x; 1.0352x over previous
//
#include <hip/hip_runtime.h>

typedef unsigned short u16;
typedef __bf16 bf16x8 __attribute__((ext_vector_type(8)));
typedef float f32x4 __attribute__((ext_vector_type(4)));

#define Bsz 64
#define Ssz 64
#define Tsz 32
#define Hsz 512
#define Vsz 32000
#define NCONV 160
#define NTOT 256

static __device__ inline u16 f2bf(float f) {
    union { float f; unsigned u; } v; v.f = f;
    unsigned u = v.u;
    unsigned r = (u + 0x7FFFu + ((u >> 16) & 1u)) >> 16;
    return (u16)r;
}
static __device__ inline float bf2f(u16 v) {
    union { unsigned u; float f; } x; x.u = ((unsigned)v) << 16; return x.f;
}
static __device__ inline float tanh_fast(float x) {
    float e = __expf(2.f * x);
    return 1.f - 2.f / (e + 1.f);
}
// agent-scope write-through stores / loads (reach/read the IC coherence point)
static __device__ inline void st_u32(unsigned* p, unsigned v) {
    __hip_atomic_store(p, v, __ATOMIC_RELAXED, __HIP_MEMORY_SCOPE_AGENT);
}
static __device__ inline unsigned ld_u32(const unsigned* p) {
    return __hip_atomic_load(p, __ATOMIC_RELAXED, __HIP_MEMORY_SCOPE_AGENT);
}

// direct-to-LDS 16B async copy
#define GLOAD_LDS16(g, l) \
    __builtin_amdgcn_global_load_lds((const __attribute__((address_space(1))) void*)(g), \
                                     (__attribute__((address_space(3))) void*)(l), 16, 0, 0)

// ---------------- f32 -> bf16 weight prep (everything except Wo) ----------------
__global__ void prep_kernel(const float* __restrict__ enc, const float* __restrict__ Ua,
                            const float* __restrict__ Wa, const float* __restrict__ wih,
                            const float* __restrict__ whh, const float* __restrict__ ehid,
                            u16* __restrict__ encbf, u16* __restrict__ Uabf,
                            u16* __restrict__ Wabf, u16* __restrict__ wihbf,
                            u16* __restrict__ whhbf, u16* __restrict__ h0bf) {
    const int n0 = 2097152, n1 = 262144, n2 = 262144, n3 = 1572864, n4 = 786432, n5 = 32768;
    const int total = n0 + n1 + n2 + n3 + n4 + n5;
    for (int i = blockIdx.x * blockDim.x + threadIdx.x; i < total; i += gridDim.x * blockDim.x) {
        int j = i;
        if (j < n0) { encbf[j] = f2bf(enc[j]); continue; } j -= n0;
        if (j < n1) { Uabf[j] = f2bf(Ua[j]); continue; } j -= n1;
        if (j < n2) { Wabf[j] = f2bf(Wa[j]); continue; } j -= n2;
        if (j < n3) { wihbf[j] = f2bf(wih[j]); continue; } j -= n3;
        if (j < n4) { whhbf[j] = f2bf(whh[j]); continue; } j -= n4;
        h0bf[j] = f2bf(ehid[j]);
    }
}

// ---------------- embedding gather into xbuf[t][b][0:512] (bf16) ----------------
__global__ void embed_kernel(const int* __restrict__ target, const float* __restrict__ emb,
                             u16* __restrict__ xbuf) {
    int n = Tsz * Bsz * Hsz;
    for (int i = blockIdx.x * blockDim.x + threadIdx.x; i < n; i += gridDim.x * blockDim.x) {
        int t = i / (Bsz * Hsz);
        int rem = i % (Bsz * Hsz);
        int b = rem / Hsz, k = rem % Hsz;
        int id = (t == 0) ? 0 : target[b * Tsz + (t - 1)];
        xbuf[((size_t)t * Bsz + b) * 1024 + k] = f2bf(emb[(size_t)id * Hsz + k]);
    }
}

// ---------------- bf16 MFMA GEMM (Ua_keys only) ----------------
__global__ __launch_bounds__(256) void gemm_bt(const u16* __restrict__ A, const u16* __restrict__ Bw,
                                               const float* __restrict__ bias, float* __restrict__ out,
                                               int M, int N, int K) {
    __shared__ __align__(16) u16 As[128 * 32];
    __shared__ __align__(16) u16 Bs[128 * 32];
    int m0 = blockIdx.x * 128, n0 = blockIdx.y * 128;
    int tid = threadIdx.x, lane = tid & 63, wid = tid >> 6;
    int wm = wid & 1, wn = wid >> 1;
    f32x4 acc[4][4] = {};
    for (int k0 = 0; k0 < K; k0 += 32) {
        int e0 = wid * 64 + lane;
        int e1 = e0 + 256;
        GLOAD_LDS16(&A[(size_t)(m0 + (e0 >> 2)) * K + k0 + (e0 & 3) * 8], (char*)As + wid * 1024);
        GLOAD_LDS16(&A[(size_t)(m0 + (e1 >> 2)) * K + k0 + (e1 & 3) * 8], (char*)As + 4096 + wid * 1024);
        GLOAD_LDS16(&Bw[(size_t)(n0 + (e0 >> 2)) * K + k0 + (e0 & 3) * 8], (char*)Bs + wid * 1024);
        GLOAD_LDS16(&Bw[(size_t)(n0 + (e1 >> 2)) * K + k0 + (e1 & 3) * 8], (char*)Bs + 4096 + wid * 1024);
        __syncthreads();
        bf16x8 av[4], bvv[4];
        for (int mi = 0; mi < 4; ++mi)
            av[mi] = *(const bf16x8*)&As[(wm * 64 + mi * 16 + (lane & 15)) * 32 + (lane >> 4) * 8];
        for (int ni = 0; ni < 4; ++ni)
            bvv[ni] = *(const bf16x8*)&Bs[(wn * 64 + ni * 16 + (lane & 15)) * 32 + (lane >> 4) * 8];
        for (int mi = 0; mi < 4; ++mi)
            for (int ni = 0; ni < 4; ++ni)
                acc[mi][ni] = __builtin_amdgcn_mfma_f32_16x16x32_bf16(av[mi], bvv[ni], acc[mi][ni], 0, 0, 0);
        __syncthreads();
    }
    for (int mi = 0; mi < 4; ++mi)
        for (int ni = 0; ni < 4; ++ni) {
            int n = n0 + wn * 64 + ni * 16 + (lane & 15);
            float bb = bias[n];
            for (int r = 0; r < 4; ++r) {
                int m = m0 + wm * 64 + mi * 16 + (lane >> 4) * 4 + r;
                out[(size_t)m * N + n] = acc[mi][ni][r] + bb;
            }
        }
}

// ---------------- flag-array sync ----------------
static __device__ inline void arrive(unsigned* bar, int slot, unsigned val, int tid) {
    asm volatile("s_waitcnt vmcnt(0)" ::: "memory");
    __syncthreads();
    if (tid == 0) st_u32(&bar[slot * 32], val);
}
static __device__ inline void pollflags(unsigned* bar, int base, int n, unsigned target, int tid) {
    if (tid < n) {
        unsigned* p = &bar[(base + tid) * 32];
        while (ld_u32(p) < target) {}
    }
    __syncthreads();
}

// ---------------- persistent recurrence kernel ----------------
// blocks 0..63  ("B"): batch b; uak[b]+enc[b] LDS-resident. Wh-sum + attention.
// blocks 64..95 ("G"): 16-col GRU slice; weights LDS-resident (swizzled); h in regs.
//                      After gates: computes Wh-PARTIALS (its k-slice of h x Wa)
//                      via zero-padded MFMA; Wa-slice frags live in registers.
// blocks 96..255: convert Wo f32->bf16 (for the later logits GEMM), then exit.
// Flag semantics: G slot publishes v=t+2 after {h_t stored, partials^{t+1} stored}
// (v=1 at init for partials^0 from h0). B slot publishes v=t+1 after ctx_t.
// B step t polls G>=t+1; G step t polls G-peers>=t+1 (h_{t-1}), per-wave polls B>=t+1.
__global__ __launch_bounds__(512, 1) void coop_kernel(
    const float* __restrict__ uak,
    u16* __restrict__ xbuf, u16* __restrict__ Abf,
    const u16* __restrict__ h0bf, const u16* __restrict__ wihbf, const u16* __restrict__ whhbf,
    const u16* __restrict__ Wabf, const float* __restrict__ enc,
    const float* __restrict__ va, const float* __restrict__ bv, const float* __restrict__ ba,
    const float* __restrict__ b_ih, const float* __restrict__ b_hh,
    const float* __restrict__ ehid,
    const float* __restrict__ Wo, u16* __restrict__ Wobf,
    float* __restrict__ out, u16* __restrict__ partials,
    unsigned* __restrict__ bar) {
    __shared__ __align__(16) char lds[149504];
    __shared__ float WhL[512];
    __shared__ float scL[64];
    __shared__ float vaL[512];

    const size_t HID_OFF = (size_t)Bsz * Tsz * Vsz;
    const size_t ATT_OFF = HID_OFF + (size_t)Bsz * Hsz;

    int tid = threadIdx.x, lane = tid & 63, wid = tid >> 6;
    int ln15 = lane & 15, hi = lane >> 4;
    int bx = blockIdx.x;

    unsigned* xbufU = (unsigned*)xbuf;
    unsigned* AbfU = (unsigned*)Abf;
    unsigned* partU = (unsigned*)partials;

    if (bx < 64) {
        // ================= B-blocks: Wh-sum + attention =================
        int b = bx;
        u16* uakL = (u16*)lds;
        u16* encL = (u16*)(lds + 65536);
        for (int i = tid; i < Ssz * Hsz; i += 512) {
            uakL[i] = f2bf(uak[(size_t)b * Ssz * Hsz + i]);
            encL[i] = f2bf(enc[(size_t)b * Ssz * Hsz + i]);
        }
        vaL[tid] = va[tid];
        float bvv = bv[0];
        float ba_t = ba[tid];
        int halfsel = tid & 1;
        __syncthreads();

        for (int t = 0; t < Tsz; ++t) {
            pollflags(bar, 64, 32, (unsigned)(t + 1), tid);      // partials^t ready
            // Wh[tid] = ba + sum_g partial[g][b][tid]  (agent loads: fresh from IC)
            {
                float acc = ba_t;
                const unsigned* pb = partU + (size_t)b * 256 + (tid >> 1);
#pragma unroll
                for (int g = 0; g < 32; ++g) {
                    unsigned pw = ld_u32(pb + (size_t)g * 16384);
                    acc += bf2f((u16)(halfsel ? (pw >> 16) : (pw & 0xffff)));
                }
                WhL[tid] = acc;
            }
            __syncthreads();
            for (int si = 0; si < 8; ++si) {
                int s = wid * 8 + si;
                float a = 0.f;
#pragma unroll
                for (int ji = 0; ji < 8; ++ji) {
                    int j = lane + ji * 64;
                    float x = WhL[j] + bf2f(uakL[s * 512 + j]);
                    a += tanh_fast(x) * vaL[j];
                }
                for (int off = 32; off; off >>= 1) a += __shfl_down(a, off);
                if (lane == 0) scL[s] = a + bvv;
            }
            __syncthreads();
            if (wid == 0) {
                float x = scL[lane];
                float mx = x;
                for (int off = 32; off; off >>= 1) mx = fmaxf(mx, __shfl_xor(mx, off));
                float e = __expf(x - mx);
                float sm = e;
                for (int off = 32; off; off >>= 1) sm += __shfl_xor(sm, off);
                float at = e / sm;
                scL[lane] = at;
                out[ATT_OFF + ((size_t)b * Tsz + t) * Ssz + lane] = at;
            }
            __syncthreads();
            float c = 0.f;
            for (int s = 0; s < Ssz; ++s)
                c += scL[s] * bf2f(encL[s * 512 + tid]);
            unsigned me = (unsigned)f2bf(c);
            unsigned other = __shfl_xor(me, 1);
            if ((tid & 1) == 0)
                st_u32(&xbufU[((size_t)t * Bsz + b) * 512 + 256 + (tid >> 1)], me | (other << 16));
            arrive(bar, bx, (unsigned)(t + 1), tid);             // ctx_t ready
        }
    } else if (bx < 96) {
        // ================= G-blocks: GRU + Wh-partials =================
        int g = bx - 64, jbase = g * 16;
        u16* hsl = (u16*)(lds + 147456);   // h-slice 64 x 16 bf16 (2 KB)
        for (int i = tid; i < 6144; i += 512) {
            int row = i >> 7, c16 = i & 127;
            int Rg = (row >> 4) * 512 + jbase + (row & 15);
            uint4 v = *(const uint4*)&wihbf[(size_t)Rg * 1024 + c16 * 8];
            *(uint4*)(lds + row * 2048 + ((c16 * 16) ^ ((row & 7) << 4))) = v;
        }
        for (int i = tid; i < 3072; i += 512) {
            int row = i >> 6, c16 = i & 63;
            int Rg = (row >> 4) * 512 + jbase + (row & 15);
            uint4 v = *(const uint4*)&whhbf[(size_t)Rg * 512 + c16 * 8];
            *(uint4*)(lds + 98304 + row * 1024 + ((c16 * 16) ^ ((row & 7) << 4))) = v;
        }
        const char* wih_l = lds;
        const char* whh_l = lds + 98304;
        int j = jbase + ln15;
        float bir = b_ih[j] + b_hh[j];
        float biz = b_ih[512 + j] + b_hh[512 + j];
        float bin = b_ih[1024 + j];
        float bhn = b_hh[1024 + j];
        float hp0 = 0.f, hp1 = 0.f, hp2 = 0.f, hp3 = 0.f;
        if (wid < 4) {
            int m = wid;
            hp0 = ehid[(size_t)(m * 16 + hi * 4 + 0) * Hsz + j];
            hp1 = ehid[(size_t)(m * 16 + hi * 4 + 1) * Hsz + j];
            hp2 = ehid[(size_t)(m * 16 + hi * 4 + 2) * Hsz + j];
            hp3 = ehid[(size_t)(m * 16 + hi * 4 + 3) * Hsz + j];
        }
        int swz = (ln15 & 7) << 4;
        // Wa k-slice fragments, register-resident (zero-padded K: hi>=2 -> 0).
        // wave wid covers n-tiles wid*4..wid*4+3 (j' = n0+ln15); B-frag k-chunk hi*8.
        bf16x8 zfr = {};
        bf16x8 wfrag[4];
#pragma unroll
        for (int i = 0; i < 4; ++i) {
            int jp = (wid * 4 + i) * 16 + ln15;
            wfrag[i] = (hi < 2) ? *(const bf16x8*)&Wabf[(size_t)jp * 512 + jbase + hi * 8] : zfr;
        }
        // ---- init: partials^0 from h0 ----
        for (int i = tid; i < 1024; i += 512)
            hsl[i] = h0bf[(size_t)(i >> 4) * 512 + jbase + (i & 15)];
        __syncthreads();
#pragma unroll
        for (int mt = 0; mt < 4; ++mt) {
            bf16x8 af = (hi < 2) ? *(const bf16x8*)&hsl[(mt * 16 + ln15) * 16 + hi * 8] : zfr;
#pragma unroll
            for (int i = 0; i < 4; ++i) {
                f32x4 pacc = {};
                pacc = __builtin_amdgcn_mfma_f32_16x16x32_bf16(af, wfrag[i], pacc, 0, 0, 0);
                int n0 = (wid * 4 + i) * 16;
#pragma unroll
                for (int r = 0; r < 4; ++r) {
                    int b = mt * 16 + hi * 4 + r;
                    unsigned me = (unsigned)f2bf(pacc[r]);
                    unsigned other = __shfl_xor(me, 1);
                    if ((ln15 & 1) == 0)
                        st_u32(&partU[((size_t)g * 64 + b) * 256 + ((n0 + ln15) >> 1)], me | (other << 16));
                }
            }
        }
        arrive(bar, bx, 1u, tid);

        for (int t = 0; t < Tsz; ++t) {
            const u16* hbt = t ? (Abf + (size_t)(t - 1) * Bsz * Hsz) : h0bf;
            pollflags(bar, 64, 32, (unsigned)(t + 1), tid);      // peers' h_{t-1}
            f32x4 ar = {}, az = {}, ain = {}, ahn = {};
            if (wid < 4) {
                int m = wid;
                // ---- prework (overlaps B's window): wih*emb + whh*h_{t-1} ----
#pragma unroll 8
                for (int k0 = 0; k0 < 16; ++k0) {
                    bf16x8 a = *(const bf16x8*)&xbuf[((size_t)t * Bsz + m * 16 + ln15) * 1024 + k0 * 32 + hi * 8];
                    int byteIn = k0 * 64 + hi * 16;
                    bf16x8 b0 = *(const bf16x8*)(wih_l + (0 + ln15) * 2048 + (byteIn ^ swz));
                    bf16x8 b1 = *(const bf16x8*)(wih_l + (16 + ln15) * 2048 + (byteIn ^ swz));
                    bf16x8 b2 = *(const bf16x8*)(wih_l + (32 + ln15) * 2048 + (byteIn ^ swz));
                    ar = __builtin_amdgcn_mfma_f32_16x16x32_bf16(a, b0, ar, 0, 0, 0);
                    az = __builtin_amdgcn_mfma_f32_16x16x32_bf16(a, b1, az, 0, 0, 0);
                    ain = __builtin_amdgcn_mfma_f32_16x16x32_bf16(a, b2, ain, 0, 0, 0);
                }
#pragma unroll 8
                for (int k0 = 0; k0 < 16; ++k0) {
                    bf16x8 a = *(const bf16x8*)&hbt[(size_t)(m * 16 + ln15) * 512 + k0 * 32 + hi * 8];
                    int byteIn = k0 * 64 + hi * 16;
                    bf16x8 b0 = *(const bf16x8*)(whh_l + (0 + ln15) * 1024 + (byteIn ^ swz));
                    bf16x8 b1 = *(const bf16x8*)(whh_l + (16 + ln15) * 1024 + (byteIn ^ swz));
                    bf16x8 b2 = *(const bf16x8*)(whh_l + (32 + ln15) * 1024 + (byteIn ^ swz));
                    ar = __builtin_amdgcn_mfma_f32_16x16x32_bf16(a, b0, ar, 0, 0, 0);
                    az = __builtin_amdgcn_mfma_f32_16x16x32_bf16(a, b1, az, 0, 0, 0);
                    ahn = __builtin_amdgcn_mfma_f32_16x16x32_bf16(a, b2, ahn, 0, 0, 0);
                }
                // per-wave ctx wait: wave m needs only batches 16m..16m+15
                unsigned* p = &bar[(wid * 16 + ln15) * 32];
                while (ld_u32(p) < (unsigned)(t + 1)) {}
                // ---- critical: wih*ctx + gates ----
#pragma unroll 8
                for (int k0 = 16; k0 < 32; ++k0) {
                    bf16x8 a = *(const bf16x8*)&xbuf[((size_t)t * Bsz + m * 16 + ln15) * 1024 + k0 * 32 + hi * 8];
                    int byteIn = k0 * 64 + hi * 16;
                    bf16x8 b0 = *(const bf16x8*)(wih_l + (0 + ln15) * 2048 + (byteIn ^ swz));
                    bf16x8 b1 = *(const bf16x8*)(wih_l + (16 + ln15) * 2048 + (byteIn ^ swz));
                    bf16x8 b2 = *(const bf16x8*)(wih_l + (32 + ln15) * 2048 + (byteIn ^ swz));
                    ar = __builtin_amdgcn_mfma_f32_16x16x32_bf16(a, b0, ar, 0, 0, 0);
                    az = __builtin_amdgcn_mfma_f32_16x16x32_bf16(a, b1, az, 0, 0, 0);
                    ain = __builtin_amdgcn_mfma_f32_16x16x32_bf16(a, b2, ain, 0, 0, 0);
                }
                float hpv[4] = {hp0, hp1, hp2, hp3};
#pragma unroll
                for (int r = 0; r < 4; ++r) {
                    int b = m * 16 + hi * 4 + r;
                    float rg = 1.f / (1.f + __expf(-(ar[r] + bir)));
                    float zg = 1.f / (1.f + __expf(-(az[r] + biz)));
                    float ng = tanh_fast(ain[r] + bin + rg * (ahn[r] + bhn));
                    float hv = (1.f - zg) * ng + zg * hpv[r];
                    hpv[r] = hv;
                    u16 hb = f2bf(hv);
                    unsigned me = (unsigned)hb;
                    unsigned other = __shfl_xor(me, 1);
                    if ((ln15 & 1) == 0)
                        st_u32(&AbfU[((size_t)t * Bsz + b) * 256 + (j >> 1)], me | (other << 16));
                    hsl[b * 16 + ln15] = hb;                     // h-slice for partials
                    if (t == Tsz - 1) out[HID_OFF + (size_t)b * 512 + j] = hv;
                }
                hp0 = hpv[0]; hp1 = hpv[1]; hp2 = hpv[2]; hp3 = hpv[3];
            }
            __syncthreads();                                     // hsl visible to all waves
            // ---- Wh-partials^{t+1} (all 8 waves, 16 MFMA each) ----
#pragma unroll
            for (int mt = 0; mt < 4; ++mt) {
                bf16x8 af = (hi < 2) ? *(const bf16x8*)&hsl[(mt * 16 + ln15) * 16 + hi * 8] : zfr;
#pragma unroll
                for (int i = 0; i < 4; ++i) {
                    f32x4 pacc = {};
                    pacc = __builtin_amdgcn_mfma_f32_16x16x32_bf16(af, wfrag[i], pacc, 0, 0, 0);
                    int n0 = (wid * 4 + i) * 16;
#pragma unroll
                    for (int r = 0; r < 4; ++r) {
                        int b = mt * 16 + hi * 4 + r;
                        unsigned me = (unsigned)f2bf(pacc[r]);
                        unsigned other = __shfl_xor(me, 1);
                        if ((ln15 & 1) == 0)
                            st_u32(&partU[((size_t)g * 64 + b) * 256 + ((n0 + ln15) >> 1)], me | (other << 16));
                    }
                }
            }
            arrive(bar, bx, (unsigned)(t + 2), tid);             // h_t + partials^{t+1}
        }
    } else {
        // ================= converter blocks: Wo f32 -> bf16 =================
        const float4* W4 = (const float4*)Wo;
        for (int i = (bx - 96) * 512 + tid; i < (Vsz * Hsz) / 4; i += NCONV * 512) {
            float4 v = W4[i];
            ushort4 o;
            o.x = f2bf(v.x); o.y = f2bf(v.y); o.z = f2bf(v.z); o.w = f2bf(v.w);
            *(ushort4*)&Wobf[(size_t)i * 4] = o;
        }
    }
}

// ---------------- logits GEMM: 128x256 tiles, dbuf LDS + counted vmcnt ----------------
static __device__ inline void l_stage(const u16* __restrict__ Abf, const u16* __restrict__ Wobf,
                                      int m0, int n0, int k0, char* As, char* Bs, int wid, int lane) {
    int e0 = wid * 64 + lane;
    int r = e0 >> 2, c8 = (e0 & 3) * 8;
    GLOAD_LDS16(&Abf[(size_t)(m0 + r) * 512 + k0 + c8], As + wid * 1024);
    GLOAD_LDS16(&Wobf[(size_t)(n0 + r) * 512 + k0 + c8], Bs + wid * 1024);
    GLOAD_LDS16(&Wobf[(size_t)(n0 + 128 + r) * 512 + k0 + c8], Bs + 8192 + wid * 1024);
}

__global__ __launch_bounds__(512) void gemm_logits(const u16* __restrict__ Abf, const u16* __restrict__ Wobf,
                                                   const float* __restrict__ bo, float* __restrict__ out,
                                                   float* __restrict__ sumexp) {
    __shared__ __align__(16) char lds[49152];
    char* As0 = lds;
    char* Bs0 = lds + 8192;
    char* As1 = lds + 24576;
    char* Bs1 = lds + 32768;
    int tid = threadIdx.x, lane = tid & 63, wid = tid >> 6;
    int ln15 = lane & 15, hi = lane >> 4;
    int wm = wid & 1, wn = wid >> 1;  // 2(M) x 4(N) waves -> wave tile 64x64
    int job = blockIdx.x;
    int m0 = (job / 125) * 128, n0 = (job % 125) * 256;
    f32x4 acc[4][4] = {};
    l_stage(Abf, Wobf, m0, n0, 0, As0, Bs0, wid, lane);
#pragma unroll 2
    for (int ks = 0; ks < 16; ++ks) {
        const u16* As = (const u16*)((ks & 1) ? As1 : As0);
        const u16* Bs = (const u16*)((ks & 1) ? Bs1 : Bs0);
        if (ks < 15) {
            l_stage(Abf, Wobf, m0, n0, (ks + 1) * 32,
                    (ks & 1) ? As0 : As1, (ks & 1) ? Bs0 : Bs1, wid, lane);
            asm volatile("s_waitcnt vmcnt(3)" ::: "memory");
        } else {
            asm volatile("s_waitcnt vmcnt(0)" ::: "memory");
        }
        __builtin_amdgcn_s_barrier();
        bf16x8 av[4], bvv[4];
        for (int mi = 0; mi < 4; ++mi)
            av[mi] = *(const bf16x8*)&As[(wm * 64 + mi * 16 + ln15) * 32 + hi * 8];
        for (int ni = 0; ni < 4; ++ni)
            bvv[ni] = *(const bf16x8*)&Bs[(wn * 64 + ni * 16 + ln15) * 32 + hi * 8];
        for (int mi = 0; mi < 4; ++mi)
            for (int ni = 0; ni < 4; ++ni)
                acc[mi][ni] = __builtin_amdgcn_mfma_f32_16x16x32_bf16(av[mi], bvv[ni], acc[mi][ni], 0, 0, 0);
        asm volatile("s_waitcnt lgkmcnt(0)" ::: "memory");
        __builtin_amdgcn_s_barrier();
    }
    float rowpart[4][4];
    for (int mi = 0; mi < 4; ++mi)
        for (int r = 0; r < 4; ++r) rowpart[mi][r] = 0.f;
    for (int mi = 0; mi < 4; ++mi)
        for (int ni = 0; ni < 4; ++ni) {
            int n = n0 + wn * 64 + ni * 16 + ln15;
            float bb = bo[n];
            for (int r = 0; r < 4; ++r) {
                int m = m0 + wm * 64 + mi * 16 + hi * 4 + r;
                int t = m >> 6, b = m & 63;
                float val = acc[mi][ni][r] + bb;
                out[((size_t)(b * Tsz + t)) * Vsz + n] = val;
                rowpart[mi][r] += __expf(val);
            }
        }
    for (int mi = 0; mi < 4; ++mi)
        for (int r = 0; r < 4; ++r) {
            float v = rowpart[mi][r];
            v += __shfl_xor(v, 1);
            v += __shfl_xor(v, 2);
            v += __shfl_xor(v, 4);
            v += __shfl_xor(v, 8);
            if (ln15 == 0) {
                int m = m0 + wm * 64 + mi * 16 + hi * 4 + r;
                atomicAdd(&sumexp[(m & 63) * Tsz + (m >> 6)], v);
            }
        }
}

// ---------------- log-softmax subtract ----------------
__global__ void sub_kernel(float* __restrict__ out, const float* __restrict__ sumexp) {
    const int total4 = (Bsz * Tsz * Vsz) / 4;
    float4* o4 = (float4*)out;
    for (int i = blockIdx.x * blockDim.x + threadIdx.x; i < total4; i += gridDim.x * blockDim.x) {
        float l = __logf(sumexp[i / (Vsz / 4)]);
        float4 v = o4[i];
        v.x -= l; v.y -= l; v.z -= l; v.w -= l;
        o4[i] = v;
    }
}

extern "C" void kernel_launch(void* const* d_in, const int* in_sizes, int n_in,
                              void* d_out, int out_size, void* d_ws, size_t ws_size,
                              hipStream_t stream) {
    const float* enc   = (const float*)d_in[0];
    const float* ehid  = (const float*)d_in[1];
    const int*   target= (const int*)d_in[2];
    const float* emb   = (const float*)d_in[3];
    const float* Wa    = (const float*)d_in[4];
    const float* ba    = (const float*)d_in[5];
    const float* Ua    = (const float*)d_in[6];
    const float* bu    = (const float*)d_in[7];
    const float* va    = (const float*)d_in[8];
    const float* bv    = (const float*)d_in[9];
    const float* w_ih  = (const float*)d_in[10];
    const float* b_ih  = (const float*)d_in[11];
    const float* w_hh  = (const float*)d_in[12];
    const float* b_hh  = (const float*)d_in[13];
    const float* Wo    = (const float*)d_in[14];
    const float* bo    = (const float*)d_in[15];
    float* out = (float*)d_out;

    char* w = (char*)d_ws;
    float* uak    = (float*)w; w += (size_t)4096 * 512 * 4;           // 8 MB
    float* sumexp = (float*)w; w += 8192;
    unsigned* bar = (unsigned*)w; w += 96 * 128;                      // 96 x 128B flag slots
    u16* xbuf     = (u16*)w;   w += (size_t)Tsz * Bsz * 1024 * 2;     // 4 MB
    u16* Abf      = (u16*)w;   w += (size_t)Tsz * Bsz * Hsz * 2;      // 2 MB
    u16* h0bf     = (u16*)w;   w += (size_t)Bsz * Hsz * 2;
    u16* partials = (u16*)w;   w += (size_t)32 * Bsz * Hsz * 2;       // 2 MB Wh partials
    u16* Wabf     = (u16*)w;   w += (size_t)Hsz * Hsz * 2;
    u16* encbf    = (u16*)w;   w += (size_t)4096 * 512 * 2;
    u16* Uabf     = (u16*)w;   w += (size_t)Hsz * Hsz * 2;
    u16* wihbf    = (u16*)w;   w += (size_t)1536 * 1024 * 2;
    u16* whhbf    = (u16*)w;   w += (size_t)1536 * 512 * 2;
    u16* Wobf     = (u16*)w;   w += (size_t)Vsz * 512 * 2;

    prep_kernel<<<2048, 256, 0, stream>>>(enc, Ua, Wa, w_ih, w_hh, ehid,
                                          encbf, Uabf, Wabf, wihbf, whhbf, h0bf);
    embed_kernel<<<1024, 256, 0, stream>>>(target, emb, xbuf);

    // Ua_keys = enc @ Ua.T + bu   (M=4096, N=512, K=512)
    gemm_bt<<<dim3(32, 4), 256, 0, stream>>>(encbf, Uabf, bu, uak, 4096, 512, 512);

    hipMemsetAsync(bar, 0, 96 * 128, stream);        // exactly the flag region
    hipMemsetAsync(sumexp, 0, 2048 * 4, stream);

    // recurrence (96 blocks) + Wo conversion (160 blocks), 1 block/CU co-resident
    coop_kernel<<<NTOT, 512, 0, stream>>>(uak, xbuf, Abf, h0bf, wihbf, whhbf,
                                          Wabf, enc, va, bv, ba, b_ih, b_hh,
                                          ehid, Wo, Wobf, out, partials, bar);

    // logits = H @ Wo.T + bo  (M=2048, N=32000, K=512), 128x256 tiles
    gemm_logits<<<2000, 512, 0, stream>>>(Abf, Wobf, bo, out, sumexp);

    sub_kernel<<<2048, 256, 0, stream>>>(out, sumexp);
}